// Round 4
// baseline (339.282 us; speedup 1.0000x reference)
//
#include <hip/hip_runtime.h>
#include <hip/hip_cooperative_groups.h>
#include <math.h>
namespace cg = cooperative_groups;

#define NSAMP 4
#define NB 64
#define LVOL (64*64*64)
#define WPS 128                 // workgroups per sample
#define NWG (NSAMP*WPS)         // 512 blocks; 2/CU on 256 CUs
#define PADR 68                 // rows 0..67 = bins -1..66 (guards for iu in [0,64])
#define KBLK 8                  // 8 k-blocks x 32 voxels = 256 voxels per iter
#define TILEB (PADR*64)         // bytes per k-block: 68 rows * 32 k * 2B = 4352
#define ABYTES (KBLK*TILEB)     // 34816 bytes per matrix
// XOR-swizzle byte-addr bits 4..6 by row bits 1..3; applied identically on
// scatter-write and frag-read (bijective involution, rows<=67 stay in pad).
#define SWZ(a,row) ((a) ^ ((((row)>>1)&7)<<4))

typedef __attribute__((ext_vector_type(8))) short bf16x8;
typedef __attribute__((ext_vector_type(4))) float f32x4;

__device__ __forceinline__ unsigned short f2bf(float x){  // RNE f32->bf16
  unsigned u = __float_as_uint(x);
  return (unsigned short)((u + 0x7FFFu + ((u >> 16) & 1u)) >> 16);
}

__global__ __launch_bounds__(256, 2) void k_fused(
    const float* __restrict__ tgt, const float* __restrict__ src,
    float4* __restrict__ mmp, float* __restrict__ P,
    float* __restrict__ hist, float* __restrict__ out)
{
  cg::grid_group gg = cg::this_grid();
  __shared__ __align__(16) char lds[2 * ABYTES];   // A then B GEMM tiles
  __shared__ float red[4][4];
  __shared__ float mmsh[4];
  __shared__ float rowsum[NB], colsum[NB], wr1[4], wr2[4], S_sh;
  const int tid = threadIdx.x;
  const int blk = blockIdx.x;
  const int n = blk >> 7, wg = blk & (WPS - 1);

  // ---- phase 0: per-block min/max over 2048 voxels (512 float4) ----
  {
    const float4* t4 = (const float4*)(tgt + (size_t)n * LVOL) + (size_t)wg * 512;
    const float4* s4 = (const float4*)(src + (size_t)n * LVOL) + (size_t)wg * 512;
    float4 a0 = t4[tid], a1 = t4[tid + 256];
    float4 b0 = s4[tid], b1 = s4[tid + 256];
    float tmn = fminf(fminf(fminf(a0.x,a0.y), fminf(a0.z,a0.w)),
                      fminf(fminf(a1.x,a1.y), fminf(a1.z,a1.w)));
    float tmx = fmaxf(fmaxf(fmaxf(a0.x,a0.y), fmaxf(a0.z,a0.w)),
                      fmaxf(fmaxf(a1.x,a1.y), fmaxf(a1.z,a1.w)));
    float smn = fminf(fminf(fminf(b0.x,b0.y), fminf(b0.z,b0.w)),
                      fminf(fminf(b1.x,b1.y), fminf(b1.z,b1.w)));
    float smx = fmaxf(fmaxf(fmaxf(b0.x,b0.y), fmaxf(b0.z,b0.w)),
                      fmaxf(fmaxf(b1.x,b1.y), fmaxf(b1.z,b1.w)));
    for (int off = 32; off; off >>= 1){
      tmn = fminf(tmn, __shfl_down(tmn, off));
      tmx = fmaxf(tmx, __shfl_down(tmx, off));
      smn = fminf(smn, __shfl_down(smn, off));
      smx = fmaxf(smx, __shfl_down(smx, off));
    }
    const int wave = tid >> 6, lane = tid & 63;
    if (lane == 0){ red[wave][0]=tmn; red[wave][1]=tmx; red[wave][2]=smn; red[wave][3]=smx; }
    __syncthreads();
    if (tid == 0){
      for (int w = 1; w < 4; ++w){
        tmn = fminf(tmn, red[w][0]); tmx = fmaxf(tmx, red[w][1]);
        smn = fminf(smn, red[w][2]); smx = fmaxf(smx, red[w][3]);
      }
      mmp[blk] = make_float4(tmn, tmx, smn, smx);
    }
  }
  __threadfence();
  gg.sync();

  // ---- phase 1: block-local reduce of this sample's 128 partials ----
  if (tid < 128){
    float4 v = mmp[n * WPS + tid];
    for (int off = 32; off; off >>= 1){
      v.x = fminf(v.x, __shfl_down(v.x, off));
      v.y = fmaxf(v.y, __shfl_down(v.y, off));
      v.z = fminf(v.z, __shfl_down(v.z, off));
      v.w = fmaxf(v.w, __shfl_down(v.w, off));
    }
    if ((tid & 63) == 0){
      red[tid >> 6][0]=v.x; red[tid >> 6][1]=v.y; red[tid >> 6][2]=v.z; red[tid >> 6][3]=v.w;
    }
  }
  __syncthreads();
  if (tid == 0){
    mmsh[0] = fminf(red[0][0], red[1][0]);
    mmsh[1] = fmaxf(red[0][1], red[1][1]);
    mmsh[2] = fminf(red[0][2], red[1][2]);
    mmsh[3] = fmaxf(red[0][3], red[1][3]);
  }
  __syncthreads();

  // ---- phase 2: joint-hist bf16 MFMA GEMM over this block's 2048 voxels ----
  {
    const float tmn = mmsh[0], smn = mmsh[2];
    const float st = (float)NB / (mmsh[1] - tmn + 1e-12f);
    const float ss = (float)NB / (mmsh[3] - smn + 1e-12f);
    const size_t vbase = (size_t)n * LVOL + (size_t)wg * 2048;
    const int kb_ = tid >> 5, k2 = tid & 31;
    const int lane = tid & 63, wv = tid >> 6;
    const int r = lane & 15, g = lane >> 4;
    const int arow = 1 + 16 * wv + r;
    const int sa = SWZ(arow * 64 + g * 16, arow);
    int sb[4];
    #pragma unroll
    for (int ct = 0; ct < 4; ++ct){
      int br = 1 + 16 * ct + r;
      sb[ct] = ABYTES + SWZ(br * 64 + g * 16, br);
    }
    f32x4 acc[4];
    #pragma unroll
    for (int ct = 0; ct < 4; ++ct) acc[ct] = (f32x4){0.f, 0.f, 0.f, 0.f};

    for (int it = 0; it < 8; ++it){
      __syncthreads();                                // prev iter reads done
      int4 zz = make_int4(0, 0, 0, 0);
      #pragma unroll
      for (int i = 0; i < 17; ++i) ((int4*)lds)[tid + i * 256] = zz;  // 69632B
      __syncthreads();
      const float tv = tgt[vbase + (size_t)it * 256 + tid];
      const float sv = src[vbase + (size_t)it * 256 + tid];
      {
        float u = (tv - tmn) * st;
        float fu = floorf(u); int iu = (int)fu; float f = u - fu, q = 1.f - f;
        float w0 = q*q*q*(1.f/6.f), w3 = f*f*f*(1.f/6.f);
        float w1 = (2.f/3.f) - f*f + 0.5f*f*f*f, w2 = 1.f - w0 - w1 - w3;
        float w[4] = {w0, w1, w2, w3};
        const int base = kb_ * TILEB + k2 * 2;
        #pragma unroll
        for (int a = 0; a < 4; ++a){
          int row = iu + a;                           // lds row = bin+1
          *(unsigned short*)(lds + SWZ(base + row * 64, row)) = f2bf(w[a]);
        }
      }
      {
        float u = (sv - smn) * ss;
        float fu = floorf(u); int iu = (int)fu; float f = u - fu, q = 1.f - f;
        float w0 = q*q*q*(1.f/6.f), w3 = f*f*f*(1.f/6.f);
        float w1 = (2.f/3.f) - f*f + 0.5f*f*f*f, w2 = 1.f - w0 - w1 - w3;
        float w[4] = {w0, w1, w2, w3};
        const int base = ABYTES + kb_ * TILEB + k2 * 2;
        #pragma unroll
        for (int a = 0; a < 4; ++a){
          int row = iu + a;
          *(unsigned short*)(lds + SWZ(base + row * 64, row)) = f2bf(w[a]);
        }
      }
      __syncthreads();
      #pragma unroll
      for (int kb = 0; kb < KBLK; ++kb){
        const char* p = lds + kb * TILEB;
        bf16x8 af = *(const bf16x8*)(p + sa);
        #pragma unroll
        for (int ct = 0; ct < 4; ++ct){
          bf16x8 bfr = *(const bf16x8*)(p + sb[ct]);
          acc[ct] = __builtin_amdgcn_mfma_f32_16x16x32_bf16(af, bfr, acc[ct], 0, 0, 0);
        }
      }
    }
    // epilogue: C/D map col=lane&15, row=(lane>>4)*4+e (m89-verified)
    float* Pp = P + (size_t)blk * 4096;
    #pragma unroll
    for (int ct = 0; ct < 4; ++ct)
      #pragma unroll
      for (int e = 0; e < 4; ++e)
        Pp[(16 * wv + g * 4 + e) * 64 + 16 * ct + r] = acc[ct][e];
  }
  __threadfence();
  gg.sync();

  // ---- phase 3: reduce 128 partials per sample into hist ----
  if (blk < 64){
    const int i = blk * 256 + tid;                    // 0..16383
    const int ns = i >> 12, bin = i & 4095;
    const float* p = P + ((size_t)ns * WPS) * 4096 + bin;
    float s = 0.f;
    for (int w = 0; w < WPS; ++w) s += p[(size_t)w * 4096];
    hist[i] = s;
  }
  __threadfence();
  gg.sync();

  // ---- phase 4: entropies + NMI, block 0 only ----
  if (blk == 0){
    float total = 0.f;
    for (int m = 0; m < NSAMP; ++m){
      if (tid < NB){ rowsum[tid] = 0.f; colsum[tid] = 0.f; }
      __syncthreads();
      const float* h = hist + m * 4096;
      const int rr = tid >> 2, c0 = (tid & 3) * 16;
      float hv[16];
      float rsum = 0.f;
      #pragma unroll
      for (int k = 0; k < 16; ++k){ hv[k] = h[rr * 64 + c0 + k]; rsum += hv[k]; }
      atomicAdd(&rowsum[rr], rsum);
      #pragma unroll
      for (int k = 0; k < 16; ++k) atomicAdd(&colsum[c0 + k], hv[k]);
      float part = rsum;
      for (int off = 32; off; off >>= 1) part += __shfl_down(part, off);
      if ((tid & 63) == 0) wr1[tid >> 6] = part;
      __syncthreads();
      if (tid == 0) S_sh = wr1[0] + wr1[1] + wr1[2] + wr1[3];
      __syncthreads();
      const float invS = 1.f / S_sh;
      float ej = 0.f;
      #pragma unroll
      for (int k = 0; k < 16; ++k){
        float p = hv[k] * invS;
        ej -= p * logf(p + 1e-12f);
      }
      for (int off = 32; off; off >>= 1) ej += __shfl_down(ej, off);
      if ((tid & 63) == 0) wr2[tid >> 6] = ej;
      float em = 0.f;
      if (tid < NB){
        float pt = rowsum[tid] * invS;
        float ps = colsum[tid] * invS;
        em = -pt * logf(pt + 1e-12f) - ps * logf(ps + 1e-12f);
        for (int off = 32; off; off >>= 1) em += __shfl_down(em, off);
      }
      __syncthreads();
      if (tid == 0){
        float EJ = wr2[0] + wr2[1] + wr2[2] + wr2[3];
        total += em / EJ;
      }
      __syncthreads();
    }
    if (tid == 0) out[0] = -0.25f * total;
  }
}

extern "C" void kernel_launch(void* const* d_in, const int* in_sizes, int n_in,
                              void* d_out, int out_size, void* d_ws, size_t ws_size,
                              hipStream_t stream){
  const float* tgt = (const float*)d_in[0];
  const float* src = (const float*)d_in[1];
  float* out = (float*)d_out;
  char* ws = (char*)d_ws;
  // ws layout: [0,8K) mmp 512*float4 | [8K,72K) hist 4*4096 f32 | [72K, +8MB) P
  float4* mmp = (float4*)ws;
  float* hist = (float*)(ws + 8192);
  float* P    = (float*)(ws + 8192 + 65536);
  void* args[] = {(void*)&tgt, (void*)&src, (void*)&mmp, (void*)&P,
                  (void*)&hist, (void*)&out};
  hipLaunchCooperativeKernel((const void*)k_fused, dim3(NWG), dim3(256),
                             args, 0, stream);
}

// Round 5
// 49.514 us; speedup vs baseline: 6.8523x; 6.8523x over previous
//
#include <hip/hip_runtime.h>
#include <math.h>

#define NSAMP 4
#define NB 64
#define LVOL (64*64*64)
#define WPS 128                 // hist workgroups per sample (512 total)
#define PADR 68                 // rows 0..67 = bins -1..66 (guards for iu in [0,64])
#define KBLK 8                  // 8 k-blocks x 32 voxels = 256 voxels per iter
#define TILEB (PADR*64)         // bytes per k-block: 68 rows * 32 k * 2B = 4352
#define ABYTES (KBLK*TILEB)     // 34816 bytes per matrix
// XOR-swizzle byte-addr bits 4..6 by row bits 1..3; applied identically on
// scatter-write, rezero, and frag-read (bijective involution, rows<=67 in pad).
#define SWZ(a,row) ((a) ^ ((((row)>>1)&7)<<4))

typedef __attribute__((ext_vector_type(8))) short bf16x8;
typedef __attribute__((ext_vector_type(4))) float f32x4;

__device__ __forceinline__ unsigned short f2bf(float x){  // RNE f32->bf16
  unsigned u = __float_as_uint(x);
  return (unsigned short)((u + 0x7FFFu + ((u >> 16) & 1u)) >> 16);
}

// ---- kernel 1: per-chunk min/max partials; also zeroes the chain counters ----
__global__ __launch_bounds__(256) void k_minmax(const float* __restrict__ tgt,
                                                const float* __restrict__ src,
                                                float4* __restrict__ mmp,
                                                int* __restrict__ cnt){
  const int n = blockIdx.x >> 6, chunk = blockIdx.x & 63;   // 64 chunks/sample
  if (blockIdx.x == 0 && threadIdx.x < 8) cnt[threadIdx.x] = 0;
  const float4* t4 = (const float4*)(tgt + (size_t)n * LVOL) + (size_t)chunk * 1024;
  const float4* s4 = (const float4*)(src + (size_t)n * LVOL) + (size_t)chunk * 1024;
  float tmn = INFINITY, tmx = -INFINITY, smn = INFINITY, smx = -INFINITY;
  #pragma unroll
  for (int i = 0; i < 4; ++i){
    float4 a = t4[threadIdx.x + i * 256];
    tmn = fminf(tmn, fminf(fminf(a.x, a.y), fminf(a.z, a.w)));
    tmx = fmaxf(tmx, fmaxf(fmaxf(a.x, a.y), fmaxf(a.z, a.w)));
    float4 b = s4[threadIdx.x + i * 256];
    smn = fminf(smn, fminf(fminf(b.x, b.y), fminf(b.z, b.w)));
    smx = fmaxf(smx, fmaxf(fmaxf(b.x, b.y), fmaxf(b.z, b.w)));
  }
  for (int off = 32; off; off >>= 1){
    tmn = fminf(tmn, __shfl_down(tmn, off));
    tmx = fmaxf(tmx, __shfl_down(tmx, off));
    smn = fminf(smn, __shfl_down(smn, off));
    smx = fmaxf(smx, __shfl_down(smx, off));
  }
  __shared__ float red[4][4];
  const int wave = threadIdx.x >> 6, lane = threadIdx.x & 63;
  if (lane == 0){ red[wave][0]=tmn; red[wave][1]=tmx; red[wave][2]=smn; red[wave][3]=smx; }
  __syncthreads();
  if (threadIdx.x == 0){
    for (int w = 1; w < 4; ++w){
      tmn = fminf(tmn, red[w][0]); tmx = fmaxf(tmx, red[w][1]);
      smn = fminf(smn, red[w][2]); smx = fmaxf(smx, red[w][3]);
    }
    mmp[blockIdx.x] = make_float4(tmn, tmx, smn, smx);
  }
}

// ---- kernel 2: joint histogram as bf16 MFMA GEMM ----
// hist[i][j] = sum_l Wt[i,l]*Ws[j,l]. Per 256-voxel iter: rezero previous
// iter's 8 scatter slots (b16), scatter 4 bf16 weights per voxel per side
// (voxel owns its K-column -> non-atomic), 2x2 wave tiling: each wave owns a
// 32x32 output quadrant (2 A-frags + 2 B-frags per k-block).
__global__ __launch_bounds__(256, 2) void k_hist(const float* __restrict__ tgt,
                                                 const float* __restrict__ src,
                                                 const float4* __restrict__ mmp,
                                                 float* __restrict__ P){
  __shared__ __align__(16) char lds[2 * ABYTES];   // A then B
  __shared__ float mmsh[4];
  const int tid = threadIdx.x;
  const int n = blockIdx.x >> 7, wg = blockIdx.x & (WPS - 1);
  // reduce this sample's 64 min/max partials (one wave)
  if (tid < 64){
    float4 v = mmp[n * 64 + tid];
    for (int off = 32; off; off >>= 1){
      v.x = fminf(v.x, __shfl_down(v.x, off));
      v.y = fmaxf(v.y, __shfl_down(v.y, off));
      v.z = fminf(v.z, __shfl_down(v.z, off));
      v.w = fmaxf(v.w, __shfl_down(v.w, off));
    }
    if (tid == 0){ mmsh[0]=v.x; mmsh[1]=v.y; mmsh[2]=v.z; mmsh[3]=v.w; }
  }
  // full zero once (69632 B = 17 * 256 * 16)
  {
    int4 zz = make_int4(0, 0, 0, 0);
    #pragma unroll
    for (int i = 0; i < 17; ++i) ((int4*)lds)[tid + i * 256] = zz;
  }
  __syncthreads();
  const float tmn = mmsh[0], smn = mmsh[2];
  const float st = (float)NB / (mmsh[1] - tmn + 1e-12f);
  const float ss = (float)NB / (mmsh[3] - smn + 1e-12f);
  const size_t vbase = (size_t)n * LVOL + (size_t)wg * 2048;
  const int kb_ = tid >> 5, k2 = tid & 31;          // voxel -> (kblock, k-in-block)
  const int lane = tid & 63, wv = tid >> 6;
  const int r = lane & 15, g = lane >> 4;
  const int rb = 32 * (wv >> 1), cb = 32 * (wv & 1);  // wave's 32x32 quadrant
  int sa[2], sb[2];
  #pragma unroll
  for (int ai = 0; ai < 2; ++ai){
    int ar = 1 + rb + 16 * ai + r;
    sa[ai] = SWZ(ar * 64 + g * 16, ar);
  }
  #pragma unroll
  for (int bj = 0; bj < 2; ++bj){
    int br = 1 + cb + 16 * bj + r;
    sb[bj] = ABYTES + SWZ(br * 64 + g * 16, br);
  }
  f32x4 acc[2][2];
  #pragma unroll
  for (int ai = 0; ai < 2; ++ai)
    #pragma unroll
    for (int bj = 0; bj < 2; ++bj) acc[ai][bj] = (f32x4){0.f, 0.f, 0.f, 0.f};

  const int baseT = kb_ * TILEB + k2 * 2;
  const int baseS = ABYTES + baseT;
  int piu_t = 0, piu_s = 0;
  for (int it = 0; it < 8; ++it){
    __syncthreads();                                // all reads of prev tile done
    if (it){                                        // rezero exactly what we wrote
      #pragma unroll
      for (int a = 0; a < 4; ++a){
        int rt = piu_t + a, rs = piu_s + a;
        *(unsigned short*)(lds + SWZ(baseT + rt * 64, rt)) = 0;
        *(unsigned short*)(lds + SWZ(baseS + rs * 64, rs)) = 0;
      }
    }
    const float tv = tgt[vbase + (size_t)it * 256 + tid];
    const float sv = src[vbase + (size_t)it * 256 + tid];
    {
      float u = (tv - tmn) * st;
      float fu = floorf(u); int iu = (int)fu; float f = u - fu, q = 1.f - f;
      float w0 = q*q*q*(1.f/6.f), w3 = f*f*f*(1.f/6.f);
      float w1 = (2.f/3.f) - f*f + 0.5f*f*f*f, w2 = 1.f - w0 - w1 - w3;
      float w[4] = {w0, w1, w2, w3};
      piu_t = iu;
      #pragma unroll
      for (int a = 0; a < 4; ++a){
        int row = iu + a;                           // lds row = bin+1
        *(unsigned short*)(lds + SWZ(baseT + row * 64, row)) = f2bf(w[a]);
      }
    }
    {
      float u = (sv - smn) * ss;
      float fu = floorf(u); int iu = (int)fu; float f = u - fu, q = 1.f - f;
      float w0 = q*q*q*(1.f/6.f), w3 = f*f*f*(1.f/6.f);
      float w1 = (2.f/3.f) - f*f + 0.5f*f*f*f, w2 = 1.f - w0 - w1 - w3;
      float w[4] = {w0, w1, w2, w3};
      piu_s = iu;
      #pragma unroll
      for (int a = 0; a < 4; ++a){
        int row = iu + a;
        *(unsigned short*)(lds + SWZ(baseS + row * 64, row)) = f2bf(w[a]);
      }
    }
    __syncthreads();
    #pragma unroll
    for (int kb = 0; kb < KBLK; ++kb){
      const char* p = lds + kb * TILEB;
      bf16x8 a0 = *(const bf16x8*)(p + sa[0]);
      bf16x8 a1 = *(const bf16x8*)(p + sa[1]);
      bf16x8 b0 = *(const bf16x8*)(p + sb[0]);
      bf16x8 b1 = *(const bf16x8*)(p + sb[1]);
      acc[0][0] = __builtin_amdgcn_mfma_f32_16x16x32_bf16(a0, b0, acc[0][0], 0, 0, 0);
      acc[0][1] = __builtin_amdgcn_mfma_f32_16x16x32_bf16(a0, b1, acc[0][1], 0, 0, 0);
      acc[1][0] = __builtin_amdgcn_mfma_f32_16x16x32_bf16(a1, b0, acc[1][0], 0, 0, 0);
      acc[1][1] = __builtin_amdgcn_mfma_f32_16x16x32_bf16(a1, b1, acc[1][1], 0, 0, 0);
    }
  }
  // epilogue: C/D map col=lane&15 (r), row=(lane>>4)*4+e (m89-verified)
  float* Pp = P + (size_t)blockIdx.x * 4096;
  #pragma unroll
  for (int ai = 0; ai < 2; ++ai)
    #pragma unroll
    for (int bj = 0; bj < 2; ++bj)
      #pragma unroll
      for (int e = 0; e < 4; ++e)
        Pp[(rb + 16 * ai + g * 4 + e) * 64 + cb + 16 * bj + r] = acc[ai][bj][e];
}

// ---- kernel 3: reduce partials -> hist -> entropies -> output, chained ----
// 64 blocks; block (n, c=0..15) reduces bins [c*256, c*256+256). The last
// finisher per sample (device atomic counter) computes that sample's
// entropies; the last sample-finisher writes the output. Cross-block reads
// inside this kernel use atomicAdd(p, 0.f) reads (per-XCD L2 not coherent
// for plain loads; clean-stale lines possible across graph replays).
__global__ __launch_bounds__(256) void k_finish(const float* __restrict__ P,
                                                float* __restrict__ hist,
                                                float* __restrict__ ratio,
                                                int* __restrict__ cnt,
                                                float* __restrict__ out){
  __shared__ float4 sh4[4][64];
  __shared__ int flag;
  __shared__ float rowsum[NB], colsum[NB], wr1[4], wr2[4], S_sh;
  const int tid = threadIdx.x;
  const int n = blockIdx.x >> 4, c = blockIdx.x & 15;
  // phase A: hist[n][c*256 .. c*256+256) = sum over 128 partials (float4)
  {
    const int f4 = tid & 63, wrange = tid >> 6;
    const float4* P4 = (const float4*)P;
    size_t base = ((size_t)n * WPS + (size_t)wrange * 32) * 1024 + c * 64 + f4;
    float4 acc = make_float4(0.f, 0.f, 0.f, 0.f);
    for (int w = 0; w < 32; ++w){
      float4 v = P4[base + (size_t)w * 1024];
      acc.x += v.x; acc.y += v.y; acc.z += v.z; acc.w += v.w;
    }
    sh4[wrange][f4] = acc;
    __syncthreads();
    if (tid < 64){
      float4 a = sh4[0][tid], b = sh4[1][tid], d = sh4[2][tid], e = sh4[3][tid];
      float4 s;
      s.x = a.x + b.x + d.x + e.x; s.y = a.y + b.y + d.y + e.y;
      s.z = a.z + b.z + d.z + e.z; s.w = a.w + b.w + d.w + e.w;
      ((float4*)hist)[(size_t)n * 1024 + c * 64 + tid] = s;
    }
  }
  __threadfence();
  __syncthreads();
  if (tid == 0) flag = atomicAdd(&cnt[n], 1);
  __syncthreads();
  if (flag != 15) return;                           // not the last chunk
  __threadfence();
  // phase B: entropies for sample n (this block only)
  float* h = hist + n * 4096;
  if (tid < NB){ rowsum[tid] = 0.f; colsum[tid] = 0.f; }
  __syncthreads();
  const int rr = tid >> 2, c0 = (tid & 3) * 16;
  float hv[16];
  float rsum = 0.f;
  #pragma unroll
  for (int k = 0; k < 16; ++k){
    hv[k] = atomicAdd(&h[rr * 64 + c0 + k], 0.f);   // coherent read
    rsum += hv[k];
  }
  atomicAdd(&rowsum[rr], rsum);
  #pragma unroll
  for (int k = 0; k < 16; ++k) atomicAdd(&colsum[c0 + k], hv[k]);
  float part = rsum;
  for (int off = 32; off; off >>= 1) part += __shfl_down(part, off);
  if ((tid & 63) == 0) wr1[tid >> 6] = part;
  __syncthreads();
  if (tid == 0) S_sh = wr1[0] + wr1[1] + wr1[2] + wr1[3];
  __syncthreads();
  const float invS = 1.f / S_sh;
  float ej = 0.f;
  #pragma unroll
  for (int k = 0; k < 16; ++k){
    float p = hv[k] * invS;
    ej -= p * logf(p + 1e-12f);
  }
  for (int off = 32; off; off >>= 1) ej += __shfl_down(ej, off);
  if ((tid & 63) == 0) wr2[tid >> 6] = ej;
  float em = 0.f;
  if (tid < NB){
    float pt = rowsum[tid] * invS;
    float ps = colsum[tid] * invS;
    em = -pt * logf(pt + 1e-12f) - ps * logf(ps + 1e-12f);
    for (int off = 32; off; off >>= 1) em += __shfl_down(em, off);
  }
  __syncthreads();
  if (tid == 0){
    float EJ = wr2[0] + wr2[1] + wr2[2] + wr2[3];
    ratio[n] = em / EJ;                             // (Ht + Hs) / Hj
    __threadfence();
    int f2 = atomicAdd(&cnt[4], 1);
    if (f2 == 3){                                   // last sample finisher
      __threadfence();
      float s = 0.f;
      #pragma unroll
      for (int m = 0; m < NSAMP; ++m) s += atomicAdd(&ratio[m], 0.f);
      out[0] = -0.25f * s;
    }
  }
}

extern "C" void kernel_launch(void* const* d_in, const int* in_sizes, int n_in,
                              void* d_out, int out_size, void* d_ws, size_t ws_size,
                              hipStream_t stream){
  const float* tgt = (const float*)d_in[0];
  const float* src = (const float*)d_in[1];
  float* out = (float*)d_out;
  char* ws = (char*)d_ws;
  // ws: [0,4K) mmp 256*float4 | [4K,+32) cnt | [4352,+16) ratio |
  //     [4608,+64K) hist | [72K, +8MB) P partials
  float4* mmp = (float4*)ws;
  int*   cnt  = (int*)(ws + 4096);
  float* ratio= (float*)(ws + 4352);
  float* hist = (float*)(ws + 4608);
  float* P    = (float*)(ws + 73728);
  k_minmax<<<NSAMP * 64, 256, 0, stream>>>(tgt, src, mmp, cnt);
  k_hist  <<<NSAMP * WPS, 256, 0, stream>>>(tgt, src, mmp, P);
  k_finish<<<NSAMP * 16, 256, 0, stream>>>(P, hist, ratio, cnt, out);
}